// Round 20
// baseline (67.285 us; speedup 1.0000x reference)
//
#include <hip/hip_runtime.h>
#include <hip/hip_fp16.h>
#include <math.h>

#define NB 128        // batch
#define N 256         // FFT size / image dim
#define NBINS 181
#define THRESH 90
#define RS 136        // row stride (half2) of intermediate F
#define GS 264        // row-kernel LDS group stride (float2)
#define BST 137       // bin-kernel LDS column stride in half2 (odd -> <=2-way)

__device__ __forceinline__ int br4(int i) {
    return ((i&1)<<3) | ((i&2)<<1) | ((i&4)>>1) | ((i&8)>>3);
}

// W16^e = exp(-2*pi*i*e/16), e = 0..7
__device__ const float TW16R[8] = { 1.f,  0.92387953f,  0.70710678f,  0.38268343f,
                                    0.f, -0.38268343f, -0.70710678f, -0.92387953f };
__device__ const float TW16I[8] = { 0.f, -0.38268343f, -0.70710678f, -0.92387953f,
                                   -1.f, -0.92387953f, -0.70710678f, -0.38268343f };
// W256^l, l = 0..15
__device__ const float W256R[16] = {
    1.00000000f, 0.99969882f, 0.99879546f, 0.99729046f, 0.99518473f, 0.99247953f,
    0.98917651f, 0.98527764f, 0.98078528f, 0.97570213f, 0.97003125f, 0.96377607f,
    0.95694034f, 0.94952818f, 0.94154407f, 0.93299280f };
__device__ const float W256I[16] = {
    -0.00000000f, -0.02454123f, -0.04906767f, -0.07356456f, -0.09801714f, -0.12241068f,
    -0.14673047f, -0.17096189f, -0.19509032f, -0.21910124f, -0.24298018f, -0.26671276f,
    -0.29028468f, -0.31368174f, -0.33688985f, -0.35989504f };

// 16-pt DIT FFT, input bit-reversed, output natural. All registers, static indices.
__device__ __forceinline__ void fft16(float2 v[16]) {
    #pragma unroll
    for (int s = 0; s < 4; ++s) {
        const int half = 1 << s;
        #pragma unroll
        for (int gg = 0; gg < 16; gg += 2*half) {
            #pragma unroll
            for (int j = 0; j < half; ++j) {
                const float wr = TW16R[j << (3 - s)];
                const float wi = TW16I[j << (3 - s)];
                float2 a = v[gg + j], b = v[gg + j + half];
                float tr = b.x*wr - b.y*wi;
                float ti = b.x*wi + b.y*wr;
                v[gg + j]        = make_float2(a.x + tr, a.y + ti);
                v[gg + j + half] = make_float2(a.x - tr, a.y - ti);
            }
        }
    }
}

__device__ __forceinline__ void twiddle256(float2 v[16], int l) {
    const float c = W256R[l], s = W256I[l];
    float wr = c, wi = s;
    #pragma unroll
    for (int k = 1; k < 16; ++k) {
        float xr = v[k].x, xi = v[k].y;
        v[k] = make_float2(xr*wr - xi*wi, xr*wi + xi*wr);
        float nr = wr*c - wi*s;
        float ni = wr*s + wi*c;
        wr = nr; wi = ni;
    }
}

// ---------------- Row pass: gray + packed-pair FFT -> half2 F, k=0..128 ----------------
// grid (16, NB), 128 threads. Block = 8 row pairs; 16 threads per FFT.
__global__ __launch_bounds__(128) void row_fft_kernel(const float* __restrict__ x,
                                                      __half2* __restrict__ F) {
    __shared__ float2 zbuf[8*GS];      // 16.9 KB

    const int t = threadIdx.x;
    const int b = blockIdx.y;
    const int pbase = blockIdx.x * 8;

    const int cidx = t & 63;
    const int sub  = t >> 6;           // 0..1
    const float* xb = x + (size_t)b * 3 * N * N;
    #pragma unroll
    for (int i = 0; i < 4; ++i) {
        int p  = i*2 + sub;
        int r0 = (pbase + p) * 2;
        const float* p0 = xb + (size_t)r0 * N + cidx*4;
        float4 a0 = *(const float4*)(p0);
        float4 a1 = *(const float4*)(p0 + N*N);
        float4 a2 = *(const float4*)(p0 + 2*N*N);
        float4 b0 = *(const float4*)(p0 + N);
        float4 b1 = *(const float4*)(p0 + N*N + N);
        float4 b2 = *(const float4*)(p0 + 2*N*N + N);
        float gx[4], gy[4];
        #pragma unroll
        for (int j = 0; j < 4; ++j) {
            gx[j] = 0.2989f*((&a0.x)[j]) + 0.587f*((&a1.x)[j]) + 0.114f*((&a2.x)[j]);
            gy[j] = 0.2989f*((&b0.x)[j]) + 0.587f*((&b1.x)[j]) + 0.114f*((&b2.x)[j]);
        }
        *(float4*)&zbuf[p*GS + cidx*4]     = make_float4(gx[0], gy[0], gx[1], gy[1]);
        *(float4*)&zbuf[p*GS + cidx*4 + 2] = make_float4(gx[2], gy[2], gx[3], gy[3]);
    }
    __syncthreads();

    const int g = t >> 4, l = t & 15;  // g 0..7
    float2 v[16];
    #pragma unroll
    for (int i = 0; i < 16; ++i) v[i] = zbuf[g*GS + 16*br4(i) + l];
    fft16(v);
    twiddle256(v, l);
    #pragma unroll
    for (int k = 0; k < 16; ++k) zbuf[g*GS + k*16 + ((l + k) & 15)] = v[k];
    #pragma unroll
    for (int i = 0; i < 16; ++i) v[i] = zbuf[g*GS + l*16 + ((br4(i) + l) & 15)];
    fft16(v);                           // thread l holds Z[l + 16*k2]

    const int lane = t & 63;
    const int src  = (lane & 48) | ((16 - l) & 15);
    __half2* o0 = F + ((size_t)b * N + (size_t)(pbase + g) * 2) * RS;
    __half2* o1 = o0 + RS;
    #pragma unroll
    for (int k2 = 0; k2 < 8; ++k2) {
        float2 zm_s;
        zm_s.x = __shfl(v[15 - k2].x, src, 64);
        zm_s.y = __shfl(v[15 - k2].y, src, 64);
        float2 zm = (l == 0) ? v[(16 - k2) & 15] : zm_s;
        float2 z  = v[k2];
        int k = l + 16*k2;
        o0[k] = __floats2half2_rn(0.5f*(z.x + zm.x), 0.5f*(z.y - zm.y));
        o1[k] = __floats2half2_rn(0.5f*(z.y + zm.y), 0.5f*(zm.x - z.x));
    }
    if (l == 0) {
        float2 z = v[8];                // k = 128, self-mirrored
        o0[128] = __floats2half2_rn(z.x, 0.f);
        o1[128] = __floats2half2_rn(z.y, 0.f);
    }
}

// ------- Col pass: half2-staged register FFT -> FOLDED log|F| half columns -------
// grid (9, NB), 256 threads. LDS 25.4 KB -> 6 blocks/CU.
__global__ __launch_bounds__(256) void col_fft_kernel(const __half2* __restrict__ F,
                                                      __half* __restrict__ mag) {
    __shared__ __half2 sbuf[16*272];   // 17.4 KB: staging (stride 17) + transpose regions
    __shared__ __half mag_lds[16*256]; // 8 KB, folded layout per column

    const int t = threadIdx.x;
    const int b  = blockIdx.y;
    const int cg = blockIdx.x;         // 0..8

    // ---- stage: coalesced raw half2 (bit-identical to F), stride-17 rows ----
    {
        const int c = t & 15, q = t >> 4;
        const int colr = cg*16 + c;
        const bool vread = (colr <= 128);
        const __half2* base = F + (size_t)b * N * RS;
        #pragma unroll
        for (int i = 0; i < 16; ++i) {
            int row = i*16 + q;
            sbuf[row*17 + c] = vread ? base[(size_t)row * RS + colr]
                                     : __floats2half2_rn(0.f, 0.f);
        }
    }
    __syncthreads();

    const int g = t >> 4, l = t & 15;
    const int col = cg*16 + g;
    const bool valid = (col <= 128);
    float2 v[16];
    if (valid) {
        #pragma unroll
        for (int i = 0; i < 16; ++i) v[i] = __half22float2(sbuf[(16*br4(i) + l)*17 + g]);
        fft16(v);
        twiddle256(v, l);
    }
    __syncthreads();                   // all stage reads done -> safe to overwrite sbuf

    if (valid) {
        // per-group 16x17 transpose region; same wave -> no barrier needed
        #pragma unroll
        for (int k = 0; k < 16; ++k) sbuf[g*272 + k*17 + l] = __float22half2_rn(v[k]);
        #pragma unroll
        for (int i = 0; i < 16; ++i) v[i] = __half22float2(sbuf[g*272 + l*17 + br4(i)]);
        fft16(v);                      // thread l holds X[u = l + 16*k2][col]
        #pragma unroll
        for (int k2 = 0; k2 < 16; ++k2) {
            float re = v[k2].x, im = v[k2].y;
            float mg = 0.5f * __logf(re*re + im*im + 1e-16f);
            int u = l + 16*k2;         // unshifted row freq
            // fold: P[128+m] -> half idx 2m+1 (u=m, u<=127); P[127-m] -> idx 2m (u=255-m)
            int idx = (u <= 127) ? (2*u + 1) : (2*(255 - u));
            mag_lds[g*256 + idx] = __float2half(mg);
        }
    }
    __syncthreads();

    // ---- coalesced store of this block's 16 folded columns ----
    #pragma unroll
    for (int j = 0; j < 2; ++j) {
        int flat = t + 256*j;          // 512 float4 = 16 cols * 512 B
        int cl = flat >> 5, ch = flat & 31;
        if (cg < 8 || cl == 0) {
            int xs = (cg*16 + cl + 128) & 255;     // fftshifted col coord
            float4 d = *(const float4*)&mag_lds[cl*256 + ch*8];
            *(float4*)&mag[((size_t)b * 256 + xs) * 256 + ch*8] = d;
        }
    }
}

// ------- Bin pass: 4 blocks/image (2/CU, 32 waves/CU), 1024 thr, float4 staging -------
// grid (4, NB). Writes prof[b][r]; each bin computed exactly once (r = q mod 4 partition).
__global__ __launch_bounds__(1024) void bin_kernel(const __half* __restrict__ mag,
                                                   float* __restrict__ prof) {
    __shared__ __half2 ml[129*BST];    // 70,692 B, folded columns, stride 137 half2
    const int t = threadIdx.x;
    const int q = blockIdx.x;          // bin residue mod 4
    const int b = blockIdx.y;
    const int lane = t & 63, wv = t >> 6;   // 16 waves

    // ---- load 129 folded columns as float4 (4128 total), decompose to b32 LDS writes ----
    {
        const float4* mb4 = (const float4*)(mag + (size_t)b * 65536);
        for (int f = t; f < 4128; f += 1024) {
            int ci = f >> 5, fc = f & 31;          // 32 float4 per column
            int xs = (ci == 0) ? 0 : 127 + ci;
            float4 d = mb4[(size_t)xs*32 + fc];
            float* dst = (float*)&ml[ci*BST + fc*4];
            dst[0] = d.x; dst[1] = d.y; dst[2] = d.z; dst[3] = d.w;
        }
    }
    __syncthreads();

    // ---- wave-per-bin: lane i handles columns i, i+64, i+128, i+192 ----
    for (int r = q + 4*wv; r < NBINS; r += 64) {
        float sum = 0.0f; int cn = 0;
        const float rr0 = (float)(r*r);
        const float rr1 = (float)((r+1)*(r+1));
        #pragma unroll
        for (int xi = 0; xi < 4; ++xi) {
            int xs = lane + 64*xi;
            float dx = (float)xs - 127.5f;
            float dx2 = dx*dx;
            float hi2 = rr1 - dx2;
            if (hi2 <= 0.0f) continue;
            float lo2 = rr0 - dx2;
            int mlo = 0;
            if (lo2 > 0.0f) mlo = (int)ceilf(sqrtf(lo2) - 0.5f);  // radius^2 has .5 frac: safe
            int mhi = (int)ceilf(sqrtf(hi2) - 0.5f);
            if (mhi > 128) mhi = 128;
            if (mlo >= mhi) continue;
            cn += 2*(mhi - mlo);
            // unified window: direct is the degenerate case of the mirror window
            const bool mirror = (xs >= 1) && (xs <= 127);
            int ci, jlo, jhi, aHi, bLo;
            if (!mirror) {
                ci = (xs == 0) ? 0 : xs - 127;
                jlo = mlo; jhi = mhi; aHi = mhi; bLo = mlo;
            } else {
                ci = 129 - xs;
                jlo = ((mlo > 0) ? mlo : 1) - 1;
                jhi = ((mhi < 128) ? mhi : 127) + 1;
                aHi = mhi - 1; bLo = mlo + 1;
            }
            const __half2* fp = &ml[ci*BST];
            if (mirror) {
                if (mlo == 0)   sum += __half2float(__high2half(fp[0]));    // fold[0].y
                if (mhi == 128) sum += __half2float(__low2half(fp[127]));   // fold[127].x
            }
            float s0=0.f, s1=0.f, s2=0.f, s3=0.f;
            int j = jlo;
            for (; j + 4 <= jhi; j += 4) {
                float2 a  = __half22float2(fp[j]);
                float2 bb = __half22float2(fp[j+1]);
                float2 c  = __half22float2(fp[j+2]);
                float2 d  = __half22float2(fp[j+3]);
                s0 += ((j   < aHi) ? a.x  : 0.f) + ((j   >= bLo) ? a.y  : 0.f);
                s1 += ((j+1 < aHi) ? bb.x : 0.f) + ((j+1 >= bLo) ? bb.y : 0.f);
                s2 += ((j+2 < aHi) ? c.x  : 0.f) + ((j+2 >= bLo) ? c.y  : 0.f);
                s3 += ((j+3 < aHi) ? d.x  : 0.f) + ((j+3 >= bLo) ? d.y  : 0.f);
            }
            for (; j < jhi; ++j) {
                float2 a = __half22float2(fp[j]);
                s0 += ((j < aHi) ? a.x : 0.f) + ((j >= bLo) ? a.y : 0.f);
            }
            sum += (s0 + s1) + (s2 + s3);
        }
        #pragma unroll
        for (int msk = 32; msk >= 1; msk >>= 1) {
            sum += __shfl_xor(sum, msk);
            cn  += __shfl_xor(cn,  msk);
        }
        if (lane == 0) prof[b*NBINS + r] = sum / (float)cn;
    }
}

// ------------- Final: min/max normalize + dot with w -------------
__global__ __launch_bounds__(256) void final_kernel(const float* __restrict__ prof,
                                                    const float* __restrict__ w,
                                                    const float* __restrict__ bias,
                                                    float* __restrict__ out) {
    __shared__ float red[16];
    const int t = threadIdx.x, b = blockIdx.x;
    const int lane = t & 63, wv = t >> 6;

    float vv = (t < NBINS) ? prof[b*NBINS + t] : prof[b*NBINS];
    float mn = vv, mx = vv;
    #pragma unroll
    for (int m = 32; m >= 1; m >>= 1) {
        mn = fminf(mn, __shfl_xor(mn, m));
        mx = fmaxf(mx, __shfl_xor(mx, m));
    }
    if (lane == 0) { red[wv] = mn; red[4 + wv] = mx; }
    __syncthreads();
    if (t == 0) {
        red[8] = fminf(fminf(red[0], red[1]), fminf(red[2], red[3]));
        red[9] = fmaxf(fmaxf(red[4], red[5]), fmaxf(red[6], red[7]));
    }
    __syncthreads();
    const float mnv = red[8], mxv = red[9];

    float part = 0.0f;
    if (t < THRESH) {
        float f = (prof[b*NBINS + (NBINS - THRESH) + t] - mnv) / (mxv - mnv);
        if (f != f) f = 0.0f;          // NaN -> 0
        part = f * w[t];
    }
    #pragma unroll
    for (int m = 32; m >= 1; m >>= 1) part += __shfl_xor(part, m);
    if (lane == 0) red[10 + wv] = part;
    __syncthreads();
    if (t == 0) out[b] = red[10] + red[11] + red[12] + red[13] + bias[0];
}

extern "C" void kernel_launch(void* const* d_in, const int* in_sizes, int n_in,
                              void* d_out, int out_size, void* d_ws, size_t ws_size,
                              hipStream_t stream) {
    const float* x    = (const float*)d_in[0];  // (128,3,256,256)
    const float* w    = (const float*)d_in[1];  // (1,90)
    const float* bias = (const float*)d_in[2];  // (1,)
    float* out = (float*)d_out;                 // (128,1)

    char* ws = (char*)d_ws;
    __half2* F  = (__half2*)ws;                                          // 17,825,792 B
    __half* mag = (__half*)(ws + (size_t)NB * N * RS * sizeof(__half2)); // 16,777,216 B
    float* prof = (float*)(ws + (size_t)NB * N * RS * sizeof(__half2)
                              + (size_t)NB * 256 * 256 * sizeof(__half)); // 92,672 B

    row_fft_kernel<<<dim3(16, NB), 128, 0, stream>>>(x, F);
    col_fft_kernel<<<dim3(9, NB), 256, 0, stream>>>(F, mag);
    bin_kernel<<<dim3(4, NB), 1024, 0, stream>>>(mag, prof);
    final_kernel<<<NB, 256, 0, stream>>>(prof, w, bias, out);
}

// Round 21
// 65.790 us; speedup vs baseline: 1.0227x; 1.0227x over previous
//
#include <hip/hip_runtime.h>
#include <hip/hip_fp16.h>
#include <math.h>

#define NB 128        // batch
#define N 256         // FFT size / image dim
#define NBINS 181
#define THRESH 90
#define RS 136        // row stride (half2) of intermediate F
#define GS 264        // row-kernel LDS group stride (float2)
#define BST 137       // bin-kernel LDS column stride in half2 (odd -> <=2-way)

__device__ __forceinline__ int br4(int i) {
    return ((i&1)<<3) | ((i&2)<<1) | ((i&4)>>1) | ((i&8)>>3);
}

// W16^e = exp(-2*pi*i*e/16), e = 0..7
__device__ const float TW16R[8] = { 1.f,  0.92387953f,  0.70710678f,  0.38268343f,
                                    0.f, -0.38268343f, -0.70710678f, -0.92387953f };
__device__ const float TW16I[8] = { 0.f, -0.38268343f, -0.70710678f, -0.92387953f,
                                   -1.f, -0.92387953f, -0.70710678f, -0.38268343f };
// W256^l, l = 0..15
__device__ const float W256R[16] = {
    1.00000000f, 0.99969882f, 0.99879546f, 0.99729046f, 0.99518473f, 0.99247953f,
    0.98917651f, 0.98527764f, 0.98078528f, 0.97570213f, 0.97003125f, 0.96377607f,
    0.95694034f, 0.94952818f, 0.94154407f, 0.93299280f };
__device__ const float W256I[16] = {
    -0.00000000f, -0.02454123f, -0.04906767f, -0.07356456f, -0.09801714f, -0.12241068f,
    -0.14673047f, -0.17096189f, -0.19509032f, -0.21910124f, -0.24298018f, -0.26671276f,
    -0.29028468f, -0.31368174f, -0.33688985f, -0.35989504f };

// 16-pt DIT FFT, input bit-reversed, output natural. All registers, static indices.
__device__ __forceinline__ void fft16(float2 v[16]) {
    #pragma unroll
    for (int s = 0; s < 4; ++s) {
        const int half = 1 << s;
        #pragma unroll
        for (int gg = 0; gg < 16; gg += 2*half) {
            #pragma unroll
            for (int j = 0; j < half; ++j) {
                const float wr = TW16R[j << (3 - s)];
                const float wi = TW16I[j << (3 - s)];
                float2 a = v[gg + j], b = v[gg + j + half];
                float tr = b.x*wr - b.y*wi;
                float ti = b.x*wi + b.y*wr;
                v[gg + j]        = make_float2(a.x + tr, a.y + ti);
                v[gg + j + half] = make_float2(a.x - tr, a.y - ti);
            }
        }
    }
}

__device__ __forceinline__ void twiddle256(float2 v[16], int l) {
    const float c = W256R[l], s = W256I[l];
    float wr = c, wi = s;
    #pragma unroll
    for (int k = 1; k < 16; ++k) {
        float xr = v[k].x, xi = v[k].y;
        v[k] = make_float2(xr*wr - xi*wi, xr*wi + xi*wr);
        float nr = wr*c - wi*s;
        float ni = wr*s + wi*c;
        wr = nr; wi = ni;
    }
}

// ---------------- Row pass: gray + packed-pair FFT -> half2 F, k=0..128 ----------------
// grid (16, NB), 128 threads. Block = 8 row pairs; 16 threads per FFT.
__global__ __launch_bounds__(128) void row_fft_kernel(const float* __restrict__ x,
                                                      __half2* __restrict__ F) {
    __shared__ float2 zbuf[8*GS];      // 16.9 KB

    const int t = threadIdx.x;
    const int b = blockIdx.y;
    const int pbase = blockIdx.x * 8;

    const int cidx = t & 63;
    const int sub  = t >> 6;           // 0..1
    const float* xb = x + (size_t)b * 3 * N * N;
    #pragma unroll
    for (int i = 0; i < 4; ++i) {
        int p  = i*2 + sub;
        int r0 = (pbase + p) * 2;
        const float* p0 = xb + (size_t)r0 * N + cidx*4;
        float4 a0 = *(const float4*)(p0);
        float4 a1 = *(const float4*)(p0 + N*N);
        float4 a2 = *(const float4*)(p0 + 2*N*N);
        float4 b0 = *(const float4*)(p0 + N);
        float4 b1 = *(const float4*)(p0 + N*N + N);
        float4 b2 = *(const float4*)(p0 + 2*N*N + N);
        float gx[4], gy[4];
        #pragma unroll
        for (int j = 0; j < 4; ++j) {
            gx[j] = 0.2989f*((&a0.x)[j]) + 0.587f*((&a1.x)[j]) + 0.114f*((&a2.x)[j]);
            gy[j] = 0.2989f*((&b0.x)[j]) + 0.587f*((&b1.x)[j]) + 0.114f*((&b2.x)[j]);
        }
        *(float4*)&zbuf[p*GS + cidx*4]     = make_float4(gx[0], gy[0], gx[1], gy[1]);
        *(float4*)&zbuf[p*GS + cidx*4 + 2] = make_float4(gx[2], gy[2], gx[3], gy[3]);
    }
    __syncthreads();

    const int g = t >> 4, l = t & 15;  // g 0..7
    float2 v[16];
    #pragma unroll
    for (int i = 0; i < 16; ++i) v[i] = zbuf[g*GS + 16*br4(i) + l];
    fft16(v);
    twiddle256(v, l);
    #pragma unroll
    for (int k = 0; k < 16; ++k) zbuf[g*GS + k*16 + ((l + k) & 15)] = v[k];
    #pragma unroll
    for (int i = 0; i < 16; ++i) v[i] = zbuf[g*GS + l*16 + ((br4(i) + l) & 15)];
    fft16(v);                           // thread l holds Z[l + 16*k2]

    const int lane = t & 63;
    const int src  = (lane & 48) | ((16 - l) & 15);
    __half2* o0 = F + ((size_t)b * N + (size_t)(pbase + g) * 2) * RS;
    __half2* o1 = o0 + RS;
    #pragma unroll
    for (int k2 = 0; k2 < 8; ++k2) {
        float2 zm_s;
        zm_s.x = __shfl(v[15 - k2].x, src, 64);
        zm_s.y = __shfl(v[15 - k2].y, src, 64);
        float2 zm = (l == 0) ? v[(16 - k2) & 15] : zm_s;
        float2 z  = v[k2];
        int k = l + 16*k2;
        o0[k] = __floats2half2_rn(0.5f*(z.x + zm.x), 0.5f*(z.y - zm.y));
        o1[k] = __floats2half2_rn(0.5f*(z.y + zm.y), 0.5f*(zm.x - z.x));
    }
    if (l == 0) {
        float2 z = v[8];                // k = 128, self-mirrored
        o0[128] = __floats2half2_rn(z.x, 0.f);
        o1[128] = __floats2half2_rn(z.y, 0.f);
    }
}

// ------- Col pass: half2-staged register FFT -> FOLDED log|F| half columns -------
// grid (9, NB), 256 threads. LDS 25.4 KB -> 6 blocks/CU.
__global__ __launch_bounds__(256) void col_fft_kernel(const __half2* __restrict__ F,
                                                      __half* __restrict__ mag) {
    __shared__ __half2 sbuf[16*272];   // 17.4 KB: staging (stride 17) + transpose regions
    __shared__ __half mag_lds[16*256]; // 8 KB, folded layout per column

    const int t = threadIdx.x;
    const int b  = blockIdx.y;
    const int cg = blockIdx.x;         // 0..8

    // ---- stage: coalesced raw half2 (bit-identical to F), stride-17 rows ----
    {
        const int c = t & 15, q = t >> 4;
        const int colr = cg*16 + c;
        const bool vread = (colr <= 128);
        const __half2* base = F + (size_t)b * N * RS;
        #pragma unroll
        for (int i = 0; i < 16; ++i) {
            int row = i*16 + q;
            sbuf[row*17 + c] = vread ? base[(size_t)row * RS + colr]
                                     : __floats2half2_rn(0.f, 0.f);
        }
    }
    __syncthreads();

    const int g = t >> 4, l = t & 15;
    const int col = cg*16 + g;
    const bool valid = (col <= 128);
    float2 v[16];
    if (valid) {
        #pragma unroll
        for (int i = 0; i < 16; ++i) v[i] = __half22float2(sbuf[(16*br4(i) + l)*17 + g]);
        fft16(v);
        twiddle256(v, l);
    }
    __syncthreads();                   // all stage reads done -> safe to overwrite sbuf

    if (valid) {
        // per-group 16x17 transpose region; same wave -> no barrier needed
        #pragma unroll
        for (int k = 0; k < 16; ++k) sbuf[g*272 + k*17 + l] = __float22half2_rn(v[k]);
        #pragma unroll
        for (int i = 0; i < 16; ++i) v[i] = __half22float2(sbuf[g*272 + l*17 + br4(i)]);
        fft16(v);                      // thread l holds X[u = l + 16*k2][col]
        #pragma unroll
        for (int k2 = 0; k2 < 16; ++k2) {
            float re = v[k2].x, im = v[k2].y;
            float mg = 0.5f * __logf(re*re + im*im + 1e-16f);
            int u = l + 16*k2;         // unshifted row freq
            // fold: P[128+m] -> half idx 2m+1 (u=m, u<=127); P[127-m] -> idx 2m (u=255-m)
            int idx = (u <= 127) ? (2*u + 1) : (2*(255 - u));
            mag_lds[g*256 + idx] = __float2half(mg);
        }
    }
    __syncthreads();

    // ---- coalesced store of this block's 16 folded columns ----
    #pragma unroll
    for (int j = 0; j < 2; ++j) {
        int flat = t + 256*j;          // 512 float4 = 16 cols * 512 B
        int cl = flat >> 5, ch = flat & 31;
        if (cg < 8 || cl == 0) {
            int xs = (cg*16 + cl + 128) & 255;     // fftshifted col coord
            float4 d = *(const float4*)&mag_lds[cl*256 + ch*8];
            *(float4*)&mag[((size_t)b * 256 + xs) * 256 + ch*8] = d;
        }
    }
}

// ------- Bin pass: 2 blocks/image, 1024 thr, float4 staging, wave-per-bin -------
// grid (2, NB). Writes prof[b][r].
__global__ __launch_bounds__(1024) void bin_kernel(const __half* __restrict__ mag,
                                                   float* __restrict__ prof) {
    __shared__ __half2 ml[129*BST];    // 70,692 B, folded columns, stride 137 half2
    const int t = threadIdx.x;
    const int q = blockIdx.x;          // bin parity
    const int b = blockIdx.y;
    const int lane = t & 63, wv = t >> 6;   // 16 waves

    // ---- load 129 folded columns as float4 (4128 total), decompose to b32 LDS writes ----
    {
        const float4* mb4 = (const float4*)(mag + (size_t)b * 65536);
        for (int f = t; f < 4128; f += 1024) {
            int ci = f >> 5, fc = f & 31;          // 32 float4 per column
            int xs = (ci == 0) ? 0 : 127 + ci;
            float4 d = mb4[(size_t)xs*32 + fc];
            float* dst = (float*)&ml[ci*BST + fc*4];
            dst[0] = d.x; dst[1] = d.y; dst[2] = d.z; dst[3] = d.w;
        }
    }
    __syncthreads();

    // ---- wave-per-bin: lane i handles columns i, i+64, i+128, i+192 ----
    for (int r = q + 2*wv; r < NBINS; r += 32) {
        float sum = 0.0f; int cn = 0;
        const float rr0 = (float)(r*r);
        const float rr1 = (float)((r+1)*(r+1));
        #pragma unroll
        for (int xi = 0; xi < 4; ++xi) {
            int xs = lane + 64*xi;
            float dx = (float)xs - 127.5f;
            float dx2 = dx*dx;
            float hi2 = rr1 - dx2;
            if (hi2 <= 0.0f) continue;
            float lo2 = rr0 - dx2;
            int mlo = 0;
            if (lo2 > 0.0f) mlo = (int)ceilf(sqrtf(lo2) - 0.5f);  // radius^2 has .5 frac: safe
            int mhi = (int)ceilf(sqrtf(hi2) - 0.5f);
            if (mhi > 128) mhi = 128;
            if (mlo >= mhi) continue;
            cn += 2*(mhi - mlo);
            // unified window: direct is the degenerate case of the mirror window
            const bool mirror = (xs >= 1) && (xs <= 127);
            int ci, jlo, jhi, aHi, bLo;
            if (!mirror) {
                ci = (xs == 0) ? 0 : xs - 127;
                jlo = mlo; jhi = mhi; aHi = mhi; bLo = mlo;
            } else {
                ci = 129 - xs;
                jlo = ((mlo > 0) ? mlo : 1) - 1;
                jhi = ((mhi < 128) ? mhi : 127) + 1;
                aHi = mhi - 1; bLo = mlo + 1;
            }
            const __half2* fp = &ml[ci*BST];
            if (mirror) {
                if (mlo == 0)   sum += __half2float(__high2half(fp[0]));    // fold[0].y
                if (mhi == 128) sum += __half2float(__low2half(fp[127]));   // fold[127].x
            }
            float s0=0.f, s1=0.f, s2=0.f, s3=0.f;
            int j = jlo;
            for (; j + 4 <= jhi; j += 4) {
                float2 a  = __half22float2(fp[j]);
                float2 bb = __half22float2(fp[j+1]);
                float2 c  = __half22float2(fp[j+2]);
                float2 d  = __half22float2(fp[j+3]);
                s0 += ((j   < aHi) ? a.x  : 0.f) + ((j   >= bLo) ? a.y  : 0.f);
                s1 += ((j+1 < aHi) ? bb.x : 0.f) + ((j+1 >= bLo) ? bb.y : 0.f);
                s2 += ((j+2 < aHi) ? c.x  : 0.f) + ((j+2 >= bLo) ? c.y  : 0.f);
                s3 += ((j+3 < aHi) ? d.x  : 0.f) + ((j+3 >= bLo) ? d.y  : 0.f);
            }
            for (; j < jhi; ++j) {
                float2 a = __half22float2(fp[j]);
                s0 += ((j < aHi) ? a.x : 0.f) + ((j >= bLo) ? a.y : 0.f);
            }
            sum += (s0 + s1) + (s2 + s3);
        }
        #pragma unroll
        for (int msk = 32; msk >= 1; msk >>= 1) {
            sum += __shfl_xor(sum, msk);
            cn  += __shfl_xor(cn,  msk);
        }
        if (lane == 0) prof[b*NBINS + r] = sum / (float)cn;
    }
}

// ------------- Final: min/max normalize + dot with w -------------
__global__ __launch_bounds__(256) void final_kernel(const float* __restrict__ prof,
                                                    const float* __restrict__ w,
                                                    const float* __restrict__ bias,
                                                    float* __restrict__ out) {
    __shared__ float red[16];
    const int t = threadIdx.x, b = blockIdx.x;
    const int lane = t & 63, wv = t >> 6;

    float vv = (t < NBINS) ? prof[b*NBINS + t] : prof[b*NBINS];
    float mn = vv, mx = vv;
    #pragma unroll
    for (int m = 32; m >= 1; m >>= 1) {
        mn = fminf(mn, __shfl_xor(mn, m));
        mx = fmaxf(mx, __shfl_xor(mx, m));
    }
    if (lane == 0) { red[wv] = mn; red[4 + wv] = mx; }
    __syncthreads();
    if (t == 0) {
        red[8] = fminf(fminf(red[0], red[1]), fminf(red[2], red[3]));
        red[9] = fmaxf(fmaxf(red[4], red[5]), fmaxf(red[6], red[7]));
    }
    __syncthreads();
    const float mnv = red[8], mxv = red[9];

    float part = 0.0f;
    if (t < THRESH) {
        float f = (prof[b*NBINS + (NBINS - THRESH) + t] - mnv) / (mxv - mnv);
        if (f != f) f = 0.0f;          // NaN -> 0
        part = f * w[t];
    }
    #pragma unroll
    for (int m = 32; m >= 1; m >>= 1) part += __shfl_xor(part, m);
    if (lane == 0) red[10 + wv] = part;
    __syncthreads();
    if (t == 0) out[b] = red[10] + red[11] + red[12] + red[13] + bias[0];
}

extern "C" void kernel_launch(void* const* d_in, const int* in_sizes, int n_in,
                              void* d_out, int out_size, void* d_ws, size_t ws_size,
                              hipStream_t stream) {
    const float* x    = (const float*)d_in[0];  // (128,3,256,256)
    const float* w    = (const float*)d_in[1];  // (1,90)
    const float* bias = (const float*)d_in[2];  // (1,)
    float* out = (float*)d_out;                 // (128,1)

    char* ws = (char*)d_ws;
    __half2* F  = (__half2*)ws;                                          // 17,825,792 B
    __half* mag = (__half*)(ws + (size_t)NB * N * RS * sizeof(__half2)); // 16,777,216 B
    float* prof = (float*)(ws + (size_t)NB * N * RS * sizeof(__half2)
                              + (size_t)NB * 256 * 256 * sizeof(__half)); // 92,672 B

    row_fft_kernel<<<dim3(16, NB), 128, 0, stream>>>(x, F);
    col_fft_kernel<<<dim3(9, NB), 256, 0, stream>>>(F, mag);
    bin_kernel<<<dim3(2, NB), 1024, 0, stream>>>(mag, prof);
    final_kernel<<<NB, 256, 0, stream>>>(prof, w, bias, out);
}